// Round 15
// baseline (207.772 us; speedup 1.0000x reference)
//
#include <hip/hip_runtime.h>
#include <hip/hip_bf16.h>
#include <math.h>

#define B_  2
#define S_  2048
#define D_  1024
#define H_  16
#define HD_ 64
#define M_  (B_*S_)      // 4096 (b,s) rows
#define BH_ (B_*H_)      // 32
#define QKSCALE 0.18033688011112042f   // 0.125 * log2(e), folded into Q

typedef __attribute__((ext_vector_type(8)))  short  bf16x8;
typedef __attribute__((ext_vector_type(4)))  float  f32x4;

#define MFMA16(a,b,c) __builtin_amdgcn_mfma_f32_16x16x32_bf16(a,b,c,0,0,0)

// ---- device scratch (~119 MB) ----
__device__ float          g_vp[(size_t)M_ * D_];     // roped V projection fp32; later PV partial z=0
__device__ float          g_p1[(size_t)M_ * D_];     // PV partial z=1
__device__ float          g_p2[(size_t)M_ * D_];     // PV partial z=2
__device__ float          g_p3[(size_t)M_ * D_];     // PV partial z=3
__device__ unsigned short g_key16[(size_t)M_ * D_];  // key   bf16
__device__ unsigned short g_val16[(size_t)M_ * D_];  // value bf16
__device__ unsigned short g_wk16[(size_t)D_ * D_];   // Wk bf16
__device__ unsigned short g_wv16[(size_t)D_ * D_];   // Wv bf16
__device__ unsigned short g_wo16[(size_t)D_ * D_];   // Wo bf16
__device__ unsigned short g_q16[(size_t)M_ * D_];    // roped+scaled Q  [bh][s][64] (flat view)
__device__ unsigned short g_k16[(size_t)M_ * D_];    // roped K
__device__ unsigned short g_v16t[(size_t)M_ * D_];   // roped,*1/Z, V^T [bh][64 d][2048 s]
__device__ unsigned short g_x16[(size_t)M_ * D_];    // attn out, (b,s,D) layout
__device__ float          g_rz[BH_ * S_];            // 1/Z per (bh, key s)
__device__ float          g_tab[S_ * 64];            // cos/sin interleaved

static __device__ __forceinline__ unsigned short f2b(float x){
  union { float f; unsigned u; } v; v.f = x;
  unsigned r = v.u + 0x7FFFu + ((v.u >> 16) & 1u);   // RNE
  return (unsigned short)(r >> 16);
}
static __device__ __forceinline__ unsigned cvtpk(float lo, float hi){
  unsigned r;
  asm("v_cvt_pk_bf16_f32 %0, %1, %2" : "=v"(r) : "v"(lo), "v"(hi));
  return r;
}
static __device__ __forceinline__ void gld16(const void* g, void* l){
  __builtin_amdgcn_global_load_lds((const __attribute__((address_space(1))) void*)g,
                                   (__attribute__((address_space(3))) void*)l, 16, 0, 0);
}

// ------------------------------------------------ cos/sin table
__global__ void k_table(const int* __restrict__ pos){
  int i = blockIdx.x * 256 + threadIdx.x;
  if (i >= S_ * 32) return;
  int s = i >> 5, f = i & 31;
  float ang = (float)pos[s] * powf(10000.0f, -(float)f * (1.0f/32.0f));
  g_tab[2*i]   = cosf(ang);
  g_tab[2*i+1] = sinf(ang);
}

// ------------------------------------------------ fp32 -> bf16 bulk convert, 5 tensors in one launch
__global__ void k_cvt5(const float* __restrict__ key, const float* __restrict__ value,
                       const float* __restrict__ Wk, const float* __restrict__ Wv,
                       const float* __restrict__ Wo){
  const int z = blockIdx.z;
  const float* src = (z==0)?key:(z==1)?value:(z==2)?Wk:(z==3)?Wv:Wo;
  unsigned short* dst = (z==0)?g_key16:(z==1)?g_val16:(z==2)?g_wk16:(z==3)?g_wv16:g_wo16;
  const int n8 = (z < 2) ? (M_*D_/8) : (D_*D_/8);
  const int i = blockIdx.x * 256 + threadIdx.x;
  if (i >= n8) return;
  float4 a = *(const float4*)(src + (size_t)i*8);
  float4 b = *(const float4*)(src + (size_t)i*8 + 4);
  uint4 w;
  w.x = cvtpk(a.x, a.y); w.y = cvtpk(a.z, a.w);
  w.z = cvtpk(b.x, b.y); w.w = cvtpk(b.z, b.w);
  *(uint4*)(dst + (size_t)i*8) = w;
}

// ------------------------------------------------ Q: RoPE + scale -> bf16 (flat head view)
__global__ void k_ropeq(const float* __restrict__ in){
  const int i = blockIdx.x * 256 + threadIdx.x;   // pair index
  const int grp = i >> 5, d = i & 31;
  const int s = grp & (S_ - 1);                   // s' in (B,H,S,hd) view
  const size_t base = (size_t)grp * 64;
  const float x1 = in[base + d];
  const float x2 = in[base + d + 32];
  const float c  = g_tab[(s*32 + d)*2];
  const float sn = g_tab[(s*32 + d)*2 + 1];
  g_q16[base + d]      = f2b((x1*c - x2*sn) * QKSCALE);
  g_q16[base + d + 32] = f2b((x2*c + x1*sn) * QKSCALE);
}

// ------------------------------------------------ fused K/V projection GEMM (bf16 in, global_load_lds staging)
// z=0: C = rope(key @ Wk^T + bk) -> g_k16 (bf16)
// z=1: C = rope(value @ Wv^T + bv) -> g_vp (fp32)
// RoPE position: projection elem (s, dd) sits at head-view s' = (s&127)*16 + (dd>>6)
__global__ __launch_bounds__(256) void k_proj(const float* __restrict__ bk,
                                              const float* __restrict__ bv){
  __shared__ __align__(16) unsigned short As[2][128*64];
  __shared__ __align__(16) unsigned short Bs[2][128*64];
  const int z = blockIdx.z;
  const unsigned short* A = z ? g_val16 : g_key16;
  const unsigned short* W = z ? g_wv16  : g_wk16;
  const float* bias = z ? bv : bk;
  const int t = threadIdx.x, l = t & 63, wid = t >> 6;
  const int wm = wid >> 1, wn = wid & 1;
  const int rowB = blockIdx.y * 128, colB = blockIdx.x * 128;
  f32x4 acc[4][4];
  #pragma unroll
  for (int i = 0; i < 4; ++i)
    #pragma unroll
    for (int j = 0; j < 4; ++j)
      #pragma unroll
      for (int r = 0; r < 4; ++r) acc[i][j][r] = 0.f;

  const int lrow = l >> 3;                            // row within 8-row chunk
  const int scol = ((l & 7) << 4) ^ (lrow << 4);      // pre-swizzled source byte-col

#define ISSUE(BUF, K0) \
  { _Pragma("unroll") \
    for (int ii = 0; ii < 4; ++ii){ \
      const int c = wid*4 + ii; \
      const int row = c*8 + lrow; \
      gld16((const char*)(A + (size_t)(rowB + row)*D_ + (K0)) + scol, (char*)As[BUF] + c*1024); \
      gld16((const char*)(W + (size_t)(colB + row)*D_ + (K0)) + scol, (char*)Bs[BUF] + c*1024); \
    } }

  ISSUE(0, 0);
  for (int kt = 0; kt < 16; ++kt){
    const int cur = kt & 1;
    __syncthreads();
    if (kt < 15){ ISSUE(cur ^ 1, (kt+1)*64); }
    #pragma unroll
    for (int kk = 0; kk < 2; ++kk){
      const int cb = kk*64 + (l >> 4) * 16;
      bf16x8 af[4], bfr[4];
      #pragma unroll
      for (int mi = 0; mi < 4; ++mi){
        const int row = wm*64 + mi*16 + (l & 15);
        af[mi] = *(const bf16x8*)((const char*)As[cur] + row*128 + (cb ^ ((row & 7) << 4)));
      }
      #pragma unroll
      for (int ni = 0; ni < 4; ++ni){
        const int row = wn*64 + ni*16 + (l & 15);
        bfr[ni] = *(const bf16x8*)((const char*)Bs[cur] + row*128 + (cb ^ ((row & 7) << 4)));
      }
      #pragma unroll
      for (int mi = 0; mi < 4; ++mi)
        #pragma unroll
        for (int ni = 0; ni < 4; ++ni)
          acc[mi][ni] = MFMA16(af[mi], bfr[ni], acc[mi][ni]);
    }
  }
#undef ISSUE
  // epilogue: bias + RoPE (pairs are ni and ni+2: cols 32 apart within a head)
  const int ql15 = l & 15, r4 = (l >> 4) * 4;
  const int hcol = (colB >> 6) + wn;              // dd>>6, wave-uniform
  #pragma unroll
  for (int mi = 0; mi < 4; ++mi){
    #pragma unroll
    for (int r = 0; r < 4; ++r){
      const int row = rowB + wm*64 + mi*16 + r4 + r;
      const int pos = ((row & 127) << 4) + hcol;  // head-view position s'
      #pragma unroll
      for (int ni = 0; ni < 2; ++ni){
        const int col = colB + wn*64 + ni*16 + ql15;   // (col & 63) < 32
        const int f = ni*16 + ql15;
        const float c  = g_tab[(pos*32 + f)*2];
        const float sn = g_tab[(pos*32 + f)*2 + 1];
        const float x1 = acc[mi][ni][r]   + bias[col];
        const float x2 = acc[mi][ni+2][r] + bias[col+32];
        const float o1 = x1*c - x2*sn;
        const float o2 = x2*c + x1*sn;
        if (z){
          g_vp[(size_t)row*D_ + col]      = o1;
          g_vp[(size_t)row*D_ + col + 32] = o2;
        } else {
          g_k16[(size_t)row*D_ + col]      = f2b(o1);
          g_k16[(size_t)row*D_ + col + 32] = f2b(o2);
        }
      }
    }
  }
}

// ------------------------------------------------ output GEMM: out = x16 @ Wo^T + bo (all bf16, gld staging)
__global__ __launch_bounds__(256) void k_gemm_out(const float* __restrict__ bias,
                                                  float* __restrict__ C){
  __shared__ __align__(16) unsigned short As[2][128*64];
  __shared__ __align__(16) unsigned short Bs[2][128*64];
  const unsigned short* A = g_x16;
  const unsigned short* W = g_wo16;
  const int t = threadIdx.x, l = t & 63, wid = t >> 6;
  const int wm = wid >> 1, wn = wid & 1;
  const int rowB = blockIdx.y * 128, colB = blockIdx.x * 128;
  f32x4 acc[4][4];
  #pragma unroll
  for (int i = 0; i < 4; ++i)
    #pragma unroll
    for (int j = 0; j < 4; ++j)
      #pragma unroll
      for (int r = 0; r < 4; ++r) acc[i][j][r] = 0.f;

  const int lrow = l >> 3;
  const int scol = ((l & 7) << 4) ^ (lrow << 4);

#define ISSUE(BUF, K0) \
  { _Pragma("unroll") \
    for (int ii = 0; ii < 4; ++ii){ \
      const int c = wid*4 + ii; \
      const int row = c*8 + lrow; \
      gld16((const char*)(A + (size_t)(rowB + row)*D_ + (K0)) + scol, (char*)As[BUF] + c*1024); \
      gld16((const char*)(W + (size_t)(colB + row)*D_ + (K0)) + scol, (char*)Bs[BUF] + c*1024); \
    } }

  ISSUE(0, 0);
  for (int kt = 0; kt < 16; ++kt){
    const int cur = kt & 1;
    __syncthreads();
    if (kt < 15){ ISSUE(cur ^ 1, (kt+1)*64); }
    #pragma unroll
    for (int kk = 0; kk < 2; ++kk){
      const int cb = kk*64 + (l >> 4) * 16;
      bf16x8 af[4], bfr[4];
      #pragma unroll
      for (int mi = 0; mi < 4; ++mi){
        const int row = wm*64 + mi*16 + (l & 15);
        af[mi] = *(const bf16x8*)((const char*)As[cur] + row*128 + (cb ^ ((row & 7) << 4)));
      }
      #pragma unroll
      for (int ni = 0; ni < 4; ++ni){
        const int row = wn*64 + ni*16 + (l & 15);
        bfr[ni] = *(const bf16x8*)((const char*)Bs[cur] + row*128 + (cb ^ ((row & 7) << 4)));
      }
      #pragma unroll
      for (int mi = 0; mi < 4; ++mi)
        #pragma unroll
        for (int ni = 0; ni < 4; ++ni)
          acc[mi][ni] = MFMA16(af[mi], bfr[ni], acc[mi][ni]);
    }
  }
#undef ISSUE
  #pragma unroll
  for (int mi = 0; mi < 4; ++mi){
    #pragma unroll
    for (int ni = 0; ni < 4; ++ni){
      const int col = colB + wn*64 + ni*16 + (l & 15);
      const float bb = bias[col];
      #pragma unroll
      for (int r = 0; r < 4; ++r){
        const int row = rowB + wm*64 + mi*16 + (l >> 4)*4 + r;
        C[(size_t)row * D_ + col] = acc[mi][ni][r] + bb;
      }
    }
  }
}

// ------------------------------------------------ pass 1: Z_k = sum_q exp(s_qk), diag s=0
// XCD-grouped 1D grid: all 32 key-blocks of one head land on one XCD (Q panel L2-resident).
// bid = (bh&7) + 8*kb + 256*(bh>>3)
__global__ __launch_bounds__(256) void k_pass1(){
  __shared__ float zs[4][4][16];
  const int t = threadIdx.x, l = t & 63, wid = t >> 6;
  const int bid = blockIdx.x;
  const int kwb = ((bid >> 3) & 31) * 64;
  const int bh  = (bid & 7) | ((bid >> 8) << 3);
  const unsigned short* Qp = g_q16 + (size_t)bh * S_ * HD_;
  const unsigned short* Kp = g_k16 + (size_t)bh * S_ * HD_;
  bf16x8 bk_[4][2];
  #pragma unroll
  for (int kb = 0; kb < 4; ++kb){
    const unsigned short* kr = Kp + (size_t)(kwb + kb*16 + (l & 15)) * HD_ + (l >> 4) * 8;
    bk_[kb][0] = *(const bf16x8*)(kr);
    bk_[kb][1] = *(const bf16x8*)(kr + 32);
  }
  float zz[4] = {0.f, 0.f, 0.f, 0.f};
  const int qBeg = wid * (S_/4);
  for (int qi = 0; qi < S_/4; qi += 16){
    const int q0 = qBeg + qi;
    const unsigned short* qr = Qp + (size_t)(q0 + (l & 15)) * HD_ + (l >> 4) * 8;
    bf16x8 a0 = *(const bf16x8*)(qr);
    bf16x8 a1 = *(const bf16x8*)(qr + 32);
    #pragma unroll
    for (int kb = 0; kb < 4; ++kb){
      f32x4 c = {0.f, 0.f, 0.f, 0.f};
      c = MFMA16(a0, bk_[kb][0], c);
      c = MFMA16(a1, bk_[kb][1], c);
      if (q0 == kwb + kb*16){          // wave-uniform: diagonal tile
        const int kg = kwb + kb*16 + (l & 15);
        #pragma unroll
        for (int r = 0; r < 4; ++r)
          zz[kb] += (q0 + (l >> 4)*4 + r == kg) ? 1.0f : exp2f(c[r]);
      } else {
        zz[kb] += exp2f(c[0]) + exp2f(c[1]) + exp2f(c[2]) + exp2f(c[3]);
      }
    }
  }
  #pragma unroll
  for (int kb = 0; kb < 4; ++kb){
    float z = zz[kb];
    z += __shfl_xor(z, 16); z += __shfl_xor(z, 32);
    if (l < 16) zs[wid][kb][l] = z;
  }
  __syncthreads();
  if (t < 64){
    const int kb = t >> 4, ki = t & 15;
    const float Z = zs[0][kb][ki] + zs[1][kb][ki] + zs[2][kb][ki] + zs[3][kb][ki];
    g_rz[bh*S_ + kwb + kb*16 + ki] = 1.0f / Z;
  }
}

// ------------------------------------------------ V fixup: *1/Z + transpose -> bf16 [bh][d][s] (already roped)
__global__ __launch_bounds__(256) void k_vfix(){
  __shared__ __align__(16) float tile[64][68];
  const int t = threadIdx.x;
  const int bh = blockIdx.y;
  const int s0 = blockIdx.x * 64;
  #pragma unroll
  for (int u = 0; u < 4; ++u){
    const int i = t + u*256;
    const int row = i >> 4, c4 = (i & 15) * 4;
    *(float4*)&tile[row][c4] = *(const float4*)(g_vp + (size_t)(bh*S_ + s0 + row) * HD_ + c4);
  }
  __syncthreads();
  const int d = t >> 2;
  const int sc = (t & 3) * 16;
  float rzv[16];
  #pragma unroll
  for (int u = 0; u < 4; ++u)
    *(float4*)&rzv[u*4] = *(const float4*)(g_rz + bh*S_ + s0 + sc + u*4);
  unsigned w[8];
  #pragma unroll
  for (int j2 = 0; j2 < 8; ++j2)
    w[j2] = cvtpk(tile[sc + 2*j2][d] * rzv[2*j2], tile[sc + 2*j2 + 1][d] * rzv[2*j2 + 1]);
  unsigned short* dst = g_v16t + (size_t)(bh*HD_ + d) * S_ + s0 + sc;
  *(uint4*)(dst)     = *(uint4*)&w[0];
  *(uint4*)(dst + 8) = *(uint4*)&w[4];
}

// ------------------------------------------------ pass 2: out[q,:] = sum_k exp(s_qk) * V'[k,:]
// 512-thread blocks: 8 waves x 32 q = 256 q share one K/V staging (LDS-per-wave halved).
// XCD-grouped 1D grid (1024): bid = (g&7) + 8*qi + 64*(g>>3), g = bh*4 + z, qi = q-block.
// P stays in REGISTERS via consistent key-slot permutation pi on both PV operands.
__global__ __launch_bounds__(512, 4) void k_pass2(){
  __shared__ __align__(16) unsigned short Ks[2][64*64];  // [buf][k][d] swizzled
  __shared__ __align__(16) unsigned short Vs[2][64*64];  // [buf][d][slot] swizzled, pi-permuted
  const int t = threadIdx.x, l = t & 63, wid = t >> 6;   // wid 0..7
  const int bid = blockIdx.x;
  const int g  = (bid & 7) | ((bid >> 6) << 3);   // 0..127
  const int bh = g >> 2;
  const int z  = g & 3;
  const int q0 = ((bid >> 3) & 7) * 256;
  const int b = bh >> 4, hh = bh & 15;
  const unsigned short* Qp = g_q16  + (size_t)bh * S_ * HD_;
  const unsigned short* Kp = g_k16  + (size_t)bh * S_ * HD_;
  const unsigned short* Vp = g_v16t + (size_t)bh * HD_ * S_;
  float* Op = (z == 0) ? g_vp : (z == 1) ? g_p1 : (z == 2) ? g_p2 : g_p3;
  const int ql = l & 15, kq = l >> 4;
  const int qb = q0 + wid*32;

  bf16x8 qf[2][2];
  #pragma unroll
  for (int h = 0; h < 2; ++h){
    const unsigned short* qr = Qp + (size_t)(qb + h*16 + ql) * HD_ + kq * 8;
    qf[h][0] = *(const bf16x8*)(qr);
    qf[h][1] = *(const bf16x8*)(qr + 32);
  }
  f32x4 co[4][2];
  #pragma unroll
  for (int nd = 0; nd < 4; ++nd)
    #pragma unroll
    for (int h = 0; h < 2; ++h)
      #pragma unroll
      for (int r = 0; r < 4; ++r) co[nd][h][r] = 0.f;

  const int srow = t >> 3, j = t & 7;     // 512 threads: one 64-row tile, one 16B chunk each
  const int scb = j * 16;
  const int vsl = j >> 2, jp = j & 3;     // V pi-staging: 32-key half, 8B group
  const int kg0 = z * (S_/4);
  float4 kreg;
  uint2 vA, vB;

#define LOADREGS(KT) \
  { const int kk0 = kg0 + (KT)*64; \
    kreg = *(const float4*)((const char*)(Kp + (size_t)(kk0 + srow) * HD_) + scb); \
    const unsigned short* vb = Vp + (size_t)srow * S_ + kk0 + vsl*32 + jp*4; \
    vA = *(const uint2*)(vb); \
    vB = *(const uint2*)(vb + 16); }
#define WRITEBUF(BUF) \
  { const int off = srow*128 + (scb ^ ((srow & 7) << 4)); \
    *(float4*)((char*)Ks[BUF] + off) = kreg; \
    uint4 wv; wv.x = vA.x; wv.y = vA.y; wv.z = vB.x; wv.w = vB.y; \
    *(uint4*)((char*)Vs[BUF] + off) = wv; }

  LOADREGS(0);
  WRITEBUF(0);
  LOADREGS(1);
  __syncthreads();

  for (int kt = 0; kt < 8; ++kt){
    const int k0 = kg0 + kt * 64;
    const int cur = kt & 1;
    if (kt < 7){ WRITEBUF(cur ^ 1); }
    if (kt < 6){ LOADREGS(kt + 2); }
    // ---- swapped QK^T: D[key16][q16]; A = K rows (LDS), B = Q (regs)
    f32x4 cst[4][2];
    #pragma unroll
    for (int kb = 0; kb < 4; ++kb)
      #pragma unroll
      for (int h = 0; h < 2; ++h)
        #pragma unroll
        for (int r = 0; r < 4; ++r) cst[kb][h][r] = 0.f;
    #pragma unroll
    for (int kb = 0; kb < 4; ++kb){
      const int row = kb*16 + ql;
      #pragma unroll
      for (int s = 0; s < 2; ++s){
        bf16x8 kf = *(const bf16x8*)((const char*)Ks[cur] + row*128 + ((s*64 + kq*16) ^ ((row & 7) << 4)));
        cst[kb][0] = MFMA16(kf, qf[0][s], cst[kb][0]);
        cst[kb][1] = MFMA16(kf, qf[1][s], cst[kb][1]);
      }
    }
    // ---- exp -> bf16 pair words, kept in registers (diag wave-uniform)
    const bool diag = (k0 < qb + 32) && (qb < k0 + 64);
    uint2 Pr[2][4];
    #pragma unroll
    for (int h = 0; h < 2; ++h){
      const int qg = qb + h*16 + ql;
      #pragma unroll
      for (int kb = 0; kb < 4; ++kb){
        float e[4];
        if (diag){
          #pragma unroll
          for (int r = 0; r < 4; ++r){
            const int key = k0 + kb*16 + kq*4 + r;
            e[r] = (qg == key) ? 1.0f : exp2f(cst[kb][h][r]);
          }
        } else {
          #pragma unroll
          for (int r = 0; r < 4; ++r) e[r] = exp2f(cst[kb][h][r]);
        }
        Pr[h][kb].x = cvtpk(e[0], e[1]);
        Pr[h][kb].y = cvtpk(e[2], e[3]);
      }
    }
    // ---- PV: D[q16][d16]; A = lane's own P words (pi order), B = Vs (pi-permuted)
    #pragma unroll
    for (int g2 = 0; g2 < 2; ++g2){          // 32-key group
      union { unsigned u[4]; bf16x8 v; } ap0, ap1;
      ap0.u[0] = Pr[0][2*g2].x;   ap0.u[1] = Pr[0][2*g2].y;
      ap0.u[2] = Pr[0][2*g2+1].x; ap0.u[3] = Pr[0][2*g2+1].y;
      ap1.u[0] = Pr[1][2*g2].x;   ap1.u[1] = Pr[1][2*g2].y;
      ap1.u[2] = Pr[1][2*g2+1].x; ap1.u[3] = Pr[1][2*g2+1].y;
      #pragma unroll
      for (int nd = 0; nd < 4; ++nd){
        const int row = nd*16 + ql;
        bf16x8 vf = *(const bf16x8*)((const char*)Vs[cur] + row*128 + ((g2*64 + kq*16) ^ ((row & 7) << 4)));
        co[nd][0] = MFMA16(ap0.v, vf, co[nd][0]);
        co[nd][1] = MFMA16(ap1.v, vf, co[nd][1]);
      }
    }
    __syncthreads();
  }
#undef LOADREGS
#undef WRITEBUF
  // epilogue: fp32 partial, (b,s,D) layout
  #pragma unroll
  for (int h = 0; h < 2; ++h){
    #pragma unroll
    for (int nd = 0; nd < 4; ++nd){
      const int d = nd*16 + ql;
      #pragma unroll
      for (int r = 0; r < 4; ++r){
        const int q = qb + h*16 + kq*4 + r;
        Op[(size_t)(b*S_ + q) * D_ + hh*HD_ + d] = co[nd][h][r];
      }
    }
  }
}

// ------------------------------------------------ combine 4 PV partials -> bf16
__global__ void k_reduce(){
  const int i = blockIdx.x * 256 + threadIdx.x;
  const size_t off = (size_t)i * 8;
  float4 a0 = *(const float4*)(g_vp + off), a1 = *(const float4*)(g_vp + off + 4);
  float4 b0 = *(const float4*)(g_p1 + off), b1 = *(const float4*)(g_p1 + off + 4);
  float4 c0 = *(const float4*)(g_p2 + off), c1 = *(const float4*)(g_p2 + off + 4);
  float4 d0 = *(const float4*)(g_p3 + off), d1 = *(const float4*)(g_p3 + off + 4);
  uint4 w;
  w.x = cvtpk(a0.x + b0.x + c0.x + d0.x, a0.y + b0.y + c0.y + d0.y);
  w.y = cvtpk(a0.z + b0.z + c0.z + d0.z, a0.w + b0.w + c0.w + d0.w);
  w.z = cvtpk(a1.x + b1.x + c1.x + d1.x, a1.y + b1.y + c1.y + d1.y);
  w.w = cvtpk(a1.z + b1.z + c1.z + d1.z, a1.w + b1.w + c1.w + d1.w);
  *(uint4*)(g_x16 + off) = w;
}

extern "C" void kernel_launch(void* const* d_in, const int* in_sizes, int n_in,
                              void* d_out, int out_size, void* d_ws, size_t ws_size,
                              hipStream_t stream) {
  const float* query = (const float*)d_in[0];
  const float* key   = (const float*)d_in[1];
  const float* value = (const float*)d_in[2];
  const int*   pos   = (const int*)  d_in[3];
  const float* Wk    = (const float*)d_in[4];
  const float* bk    = (const float*)d_in[5];
  const float* Wv    = (const float*)d_in[6];
  const float* bv    = (const float*)d_in[7];
  const float* Wo    = (const float*)d_in[8];
  const float* bo    = (const float*)d_in[9];
  float* out = (float*)d_out;

  k_table<<<256, 256, 0, stream>>>(pos);
  k_cvt5<<<dim3(2048, 1, 5), 256, 0, stream>>>(key, value, Wk, Wv, Wo);

  dim3 gP(D_/128, M_/128, 2);   // (8, 32, 2)
  k_proj<<<gP, 256, 0, stream>>>(bk, bv);                      // -> g_k16 (roped bf16), g_vp (roped fp32)

  k_ropeq<<<8192, 256, 0, stream>>>(query);                    // -> g_q16 (roped, scaled)

  k_pass1<<<1024, 256, 0, stream>>>();                         // -> g_rz  (XCD-grouped)
  k_vfix <<<dim3(32, BH_), 256, 0, stream>>>();                // g_vp -> g_v16t (*1/Z, transposed)
  k_pass2<<<1024, 512, 0, stream>>>();                         // -> 4 fp32 partials (XCD-grouped, 8-wave blocks)
  k_reduce<<<(M_*D_/8)/256, 256, 0, stream>>>();               // -> g_x16

  dim3 gO(D_/128, M_/128);      // (8, 32)
  k_gemm_out<<<gO, 256, 0, stream>>>(bo, out);                 // output proj
}

// Round 16
// 207.528 us; speedup vs baseline: 1.0012x; 1.0012x over previous
//
#include <hip/hip_runtime.h>
#include <hip/hip_bf16.h>
#include <math.h>

#define B_  2
#define S_  2048
#define D_  1024
#define H_  16
#define HD_ 64
#define M_  (B_*S_)      // 4096 (b,s) rows
#define BH_ (B_*H_)      // 32
#define QKSCALE 0.18033688011112042f   // 0.125 * log2(e), folded into Q

typedef __attribute__((ext_vector_type(8)))  short  bf16x8;
typedef __attribute__((ext_vector_type(4)))  float  f32x4;

#define MFMA16(a,b,c) __builtin_amdgcn_mfma_f32_16x16x32_bf16(a,b,c,0,0,0)

// ---- device scratch (~119 MB) ----
__device__ float          g_vp[(size_t)M_ * D_];     // roped V projection fp32; later PV partial z=0
__device__ float          g_p1[(size_t)M_ * D_];     // PV partial z=1
__device__ float          g_p2[(size_t)M_ * D_];     // PV partial z=2
__device__ float          g_p3[(size_t)M_ * D_];     // PV partial z=3
__device__ unsigned short g_key16[(size_t)M_ * D_];  // key   bf16
__device__ unsigned short g_val16[(size_t)M_ * D_];  // value bf16
__device__ unsigned short g_wk16[(size_t)D_ * D_];   // Wk bf16
__device__ unsigned short g_wv16[(size_t)D_ * D_];   // Wv bf16
__device__ unsigned short g_wo16[(size_t)D_ * D_];   // Wo bf16
__device__ unsigned short g_q16[(size_t)M_ * D_];    // roped+scaled Q  [bh][s][64] (flat view)
__device__ unsigned short g_k16[(size_t)M_ * D_];    // roped K
__device__ unsigned short g_v16t[(size_t)M_ * D_];   // roped,*1/Z, V^T [bh][64 d][2048 s]
__device__ unsigned short g_x16[(size_t)M_ * D_];    // attn out, (b,s,D) layout
__device__ float          g_rz[BH_ * S_];            // 1/Z per (bh, key s)
__device__ float          g_tab[S_ * 64];            // cos/sin interleaved

static __device__ __forceinline__ unsigned short f2b(float x){
  union { float f; unsigned u; } v; v.f = x;
  unsigned r = v.u + 0x7FFFu + ((v.u >> 16) & 1u);   // RNE
  return (unsigned short)(r >> 16);
}
static __device__ __forceinline__ unsigned cvtpk(float lo, float hi){
  unsigned r;
  asm("v_cvt_pk_bf16_f32 %0, %1, %2" : "=v"(r) : "v"(lo), "v"(hi));
  return r;
}
static __device__ __forceinline__ void gld16(const void* g, void* l){
  __builtin_amdgcn_global_load_lds((const __attribute__((address_space(1))) void*)g,
                                   (__attribute__((address_space(3))) void*)l, 16, 0, 0);
}

// ------------------------------------------------ cos/sin table
__global__ void k_table(const int* __restrict__ pos){
  int i = blockIdx.x * 256 + threadIdx.x;
  if (i >= S_ * 32) return;
  int s = i >> 5, f = i & 31;
  float ang = (float)pos[s] * powf(10000.0f, -(float)f * (1.0f/32.0f));
  g_tab[2*i]   = cosf(ang);
  g_tab[2*i+1] = sinf(ang);
}

// ------------------------------------------------ fp32 -> bf16 bulk convert, 5 tensors in one launch
__global__ void k_cvt5(const float* __restrict__ key, const float* __restrict__ value,
                       const float* __restrict__ Wk, const float* __restrict__ Wv,
                       const float* __restrict__ Wo){
  const int z = blockIdx.z;
  const float* src = (z==0)?key:(z==1)?value:(z==2)?Wk:(z==3)?Wv:Wo;
  unsigned short* dst = (z==0)?g_key16:(z==1)?g_val16:(z==2)?g_wk16:(z==3)?g_wv16:g_wo16;
  const int n8 = (z < 2) ? (M_*D_/8) : (D_*D_/8);
  const int i = blockIdx.x * 256 + threadIdx.x;
  if (i >= n8) return;
  float4 a = *(const float4*)(src + (size_t)i*8);
  float4 b = *(const float4*)(src + (size_t)i*8 + 4);
  uint4 w;
  w.x = cvtpk(a.x, a.y); w.y = cvtpk(a.z, a.w);
  w.z = cvtpk(b.x, b.y); w.w = cvtpk(b.z, b.w);
  *(uint4*)(dst + (size_t)i*8) = w;
}

// ------------------------------------------------ Q: RoPE + scale -> bf16 (flat head view)
__global__ void k_ropeq(const float* __restrict__ in){
  const int i = blockIdx.x * 256 + threadIdx.x;   // pair index
  const int grp = i >> 5, d = i & 31;
  const int s = grp & (S_ - 1);                   // s' in (B,H,S,hd) view
  const size_t base = (size_t)grp * 64;
  const float x1 = in[base + d];
  const float x2 = in[base + d + 32];
  const float c  = g_tab[(s*32 + d)*2];
  const float sn = g_tab[(s*32 + d)*2 + 1];
  g_q16[base + d]      = f2b((x1*c - x2*sn) * QKSCALE);
  g_q16[base + d + 32] = f2b((x2*c + x1*sn) * QKSCALE);
}

// ------------------------------------------------ fused K/V projection GEMM (bf16 in, global_load_lds staging)
// z=0: C = rope(key @ Wk^T + bk) -> g_k16 (bf16)
// z=1: C = rope(value @ Wv^T + bv) -> g_vp (fp32)
// RoPE position: projection elem (s, dd) sits at head-view s' = (s&127)*16 + (dd>>6)
__global__ __launch_bounds__(256) void k_proj(const float* __restrict__ bk,
                                              const float* __restrict__ bv){
  __shared__ __align__(16) unsigned short As[2][128*64];
  __shared__ __align__(16) unsigned short Bs[2][128*64];
  const int z = blockIdx.z;
  const unsigned short* A = z ? g_val16 : g_key16;
  const unsigned short* W = z ? g_wv16  : g_wk16;
  const float* bias = z ? bv : bk;
  const int t = threadIdx.x, l = t & 63, wid = t >> 6;
  const int wm = wid >> 1, wn = wid & 1;
  const int rowB = blockIdx.y * 128, colB = blockIdx.x * 128;
  f32x4 acc[4][4];
  #pragma unroll
  for (int i = 0; i < 4; ++i)
    #pragma unroll
    for (int j = 0; j < 4; ++j)
      #pragma unroll
      for (int r = 0; r < 4; ++r) acc[i][j][r] = 0.f;

  const int lrow = l >> 3;                            // row within 8-row chunk
  const int scol = ((l & 7) << 4) ^ (lrow << 4);      // pre-swizzled source byte-col

#define ISSUE(BUF, K0) \
  { _Pragma("unroll") \
    for (int ii = 0; ii < 4; ++ii){ \
      const int c = wid*4 + ii; \
      const int row = c*8 + lrow; \
      gld16((const char*)(A + (size_t)(rowB + row)*D_ + (K0)) + scol, (char*)As[BUF] + c*1024); \
      gld16((const char*)(W + (size_t)(colB + row)*D_ + (K0)) + scol, (char*)Bs[BUF] + c*1024); \
    } }

  ISSUE(0, 0);
  for (int kt = 0; kt < 16; ++kt){
    const int cur = kt & 1;
    __syncthreads();
    if (kt < 15){ ISSUE(cur ^ 1, (kt+1)*64); }
    #pragma unroll
    for (int kk = 0; kk < 2; ++kk){
      const int cb = kk*64 + (l >> 4) * 16;
      bf16x8 af[4], bfr[4];
      #pragma unroll
      for (int mi = 0; mi < 4; ++mi){
        const int row = wm*64 + mi*16 + (l & 15);
        af[mi] = *(const bf16x8*)((const char*)As[cur] + row*128 + (cb ^ ((row & 7) << 4)));
      }
      #pragma unroll
      for (int ni = 0; ni < 4; ++ni){
        const int row = wn*64 + ni*16 + (l & 15);
        bfr[ni] = *(const bf16x8*)((const char*)Bs[cur] + row*128 + (cb ^ ((row & 7) << 4)));
      }
      #pragma unroll
      for (int mi = 0; mi < 4; ++mi)
        #pragma unroll
        for (int ni = 0; ni < 4; ++ni)
          acc[mi][ni] = MFMA16(af[mi], bfr[ni], acc[mi][ni]);
    }
  }
#undef ISSUE
  // epilogue: bias + RoPE (pairs are ni and ni+2: cols 32 apart within a head)
  const int ql15 = l & 15, r4 = (l >> 4) * 4;
  const int hcol = (colB >> 6) + wn;              // dd>>6, wave-uniform
  #pragma unroll
  for (int mi = 0; mi < 4; ++mi){
    #pragma unroll
    for (int r = 0; r < 4; ++r){
      const int row = rowB + wm*64 + mi*16 + r4 + r;
      const int pos = ((row & 127) << 4) + hcol;  // head-view position s'
      #pragma unroll
      for (int ni = 0; ni < 2; ++ni){
        const int col = colB + wn*64 + ni*16 + ql15;   // (col & 63) < 32
        const int f = ni*16 + ql15;
        const float c  = g_tab[(pos*32 + f)*2];
        const float sn = g_tab[(pos*32 + f)*2 + 1];
        const float x1 = acc[mi][ni][r]   + bias[col];
        const float x2 = acc[mi][ni+2][r] + bias[col+32];
        const float o1 = x1*c - x2*sn;
        const float o2 = x2*c + x1*sn;
        if (z){
          g_vp[(size_t)row*D_ + col]      = o1;
          g_vp[(size_t)row*D_ + col + 32] = o2;
        } else {
          g_k16[(size_t)row*D_ + col]      = f2b(o1);
          g_k16[(size_t)row*D_ + col + 32] = f2b(o2);
        }
      }
    }
  }
}

// ------------------------------------------------ output GEMM: out = x16 @ Wo^T + bo (all bf16, gld staging)
__global__ __launch_bounds__(256) void k_gemm_out(const float* __restrict__ bias,
                                                  float* __restrict__ C){
  __shared__ __align__(16) unsigned short As[2][128*64];
  __shared__ __align__(16) unsigned short Bs[2][128*64];
  const unsigned short* A = g_x16;
  const unsigned short* W = g_wo16;
  const int t = threadIdx.x, l = t & 63, wid = t >> 6;
  const int wm = wid >> 1, wn = wid & 1;
  const int rowB = blockIdx.y * 128, colB = blockIdx.x * 128;
  f32x4 acc[4][4];
  #pragma unroll
  for (int i = 0; i < 4; ++i)
    #pragma unroll
    for (int j = 0; j < 4; ++j)
      #pragma unroll
      for (int r = 0; r < 4; ++r) acc[i][j][r] = 0.f;

  const int lrow = l >> 3;
  const int scol = ((l & 7) << 4) ^ (lrow << 4);

#define ISSUE(BUF, K0) \
  { _Pragma("unroll") \
    for (int ii = 0; ii < 4; ++ii){ \
      const int c = wid*4 + ii; \
      const int row = c*8 + lrow; \
      gld16((const char*)(A + (size_t)(rowB + row)*D_ + (K0)) + scol, (char*)As[BUF] + c*1024); \
      gld16((const char*)(W + (size_t)(colB + row)*D_ + (K0)) + scol, (char*)Bs[BUF] + c*1024); \
    } }

  ISSUE(0, 0);
  for (int kt = 0; kt < 16; ++kt){
    const int cur = kt & 1;
    __syncthreads();
    if (kt < 15){ ISSUE(cur ^ 1, (kt+1)*64); }
    #pragma unroll
    for (int kk = 0; kk < 2; ++kk){
      const int cb = kk*64 + (l >> 4) * 16;
      bf16x8 af[4], bfr[4];
      #pragma unroll
      for (int mi = 0; mi < 4; ++mi){
        const int row = wm*64 + mi*16 + (l & 15);
        af[mi] = *(const bf16x8*)((const char*)As[cur] + row*128 + (cb ^ ((row & 7) << 4)));
      }
      #pragma unroll
      for (int ni = 0; ni < 4; ++ni){
        const int row = wn*64 + ni*16 + (l & 15);
        bfr[ni] = *(const bf16x8*)((const char*)Bs[cur] + row*128 + (cb ^ ((row & 7) << 4)));
      }
      #pragma unroll
      for (int mi = 0; mi < 4; ++mi)
        #pragma unroll
        for (int ni = 0; ni < 4; ++ni)
          acc[mi][ni] = MFMA16(af[mi], bfr[ni], acc[mi][ni]);
    }
  }
#undef ISSUE
  #pragma unroll
  for (int mi = 0; mi < 4; ++mi){
    #pragma unroll
    for (int ni = 0; ni < 4; ++ni){
      const int col = colB + wn*64 + ni*16 + (l & 15);
      const float bb = bias[col];
      #pragma unroll
      for (int r = 0; r < 4; ++r){
        const int row = rowB + wm*64 + mi*16 + (l >> 4)*4 + r;
        C[(size_t)row * D_ + col] = acc[mi][ni][r] + bb;
      }
    }
  }
}

// ------------------------------------------------ pass 1: Z_k = sum_q exp(s_qk), diag s=0
// XCD-grouped 1D grid: all 32 key-blocks of one head land on one XCD (Q panel L2-resident).
// bid = (bh&7) + 8*kb + 256*(bh>>3)
__global__ __launch_bounds__(256) void k_pass1(){
  __shared__ float zs[4][4][16];
  const int t = threadIdx.x, l = t & 63, wid = t >> 6;
  const int bid = blockIdx.x;
  const int kwb = ((bid >> 3) & 31) * 64;
  const int bh  = (bid & 7) | ((bid >> 8) << 3);
  const unsigned short* Qp = g_q16 + (size_t)bh * S_ * HD_;
  const unsigned short* Kp = g_k16 + (size_t)bh * S_ * HD_;
  bf16x8 bk_[4][2];
  #pragma unroll
  for (int kb = 0; kb < 4; ++kb){
    const unsigned short* kr = Kp + (size_t)(kwb + kb*16 + (l & 15)) * HD_ + (l >> 4) * 8;
    bk_[kb][0] = *(const bf16x8*)(kr);
    bk_[kb][1] = *(const bf16x8*)(kr + 32);
  }
  float zz[4] = {0.f, 0.f, 0.f, 0.f};
  const int qBeg = wid * (S_/4);
  for (int qi = 0; qi < S_/4; qi += 16){
    const int q0 = qBeg + qi;
    const unsigned short* qr = Qp + (size_t)(q0 + (l & 15)) * HD_ + (l >> 4) * 8;
    bf16x8 a0 = *(const bf16x8*)(qr);
    bf16x8 a1 = *(const bf16x8*)(qr + 32);
    #pragma unroll
    for (int kb = 0; kb < 4; ++kb){
      f32x4 c = {0.f, 0.f, 0.f, 0.f};
      c = MFMA16(a0, bk_[kb][0], c);
      c = MFMA16(a1, bk_[kb][1], c);
      if (q0 == kwb + kb*16){          // wave-uniform: diagonal tile
        const int kg = kwb + kb*16 + (l & 15);
        #pragma unroll
        for (int r = 0; r < 4; ++r)
          zz[kb] += (q0 + (l >> 4)*4 + r == kg) ? 1.0f : exp2f(c[r]);
      } else {
        zz[kb] += exp2f(c[0]) + exp2f(c[1]) + exp2f(c[2]) + exp2f(c[3]);
      }
    }
  }
  #pragma unroll
  for (int kb = 0; kb < 4; ++kb){
    float z = zz[kb];
    z += __shfl_xor(z, 16); z += __shfl_xor(z, 32);
    if (l < 16) zs[wid][kb][l] = z;
  }
  __syncthreads();
  if (t < 64){
    const int kb = t >> 4, ki = t & 15;
    const float Z = zs[0][kb][ki] + zs[1][kb][ki] + zs[2][kb][ki] + zs[3][kb][ki];
    g_rz[bh*S_ + kwb + kb*16 + ki] = 1.0f / Z;
  }
}

// ------------------------------------------------ V fixup: *1/Z + transpose -> bf16 [bh][d][s] (already roped)
__global__ __launch_bounds__(256) void k_vfix(){
  __shared__ __align__(16) float tile[64][68];
  const int t = threadIdx.x;
  const int bh = blockIdx.y;
  const int s0 = blockIdx.x * 64;
  #pragma unroll
  for (int u = 0; u < 4; ++u){
    const int i = t + u*256;
    const int row = i >> 4, c4 = (i & 15) * 4;
    *(float4*)&tile[row][c4] = *(const float4*)(g_vp + (size_t)(bh*S_ + s0 + row) * HD_ + c4);
  }
  __syncthreads();
  const int d = t >> 2;
  const int sc = (t & 3) * 16;
  float rzv[16];
  #pragma unroll
  for (int u = 0; u < 4; ++u)
    *(float4*)&rzv[u*4] = *(const float4*)(g_rz + bh*S_ + s0 + sc + u*4);
  unsigned w[8];
  #pragma unroll
  for (int j2 = 0; j2 < 8; ++j2)
    w[j2] = cvtpk(tile[sc + 2*j2][d] * rzv[2*j2], tile[sc + 2*j2 + 1][d] * rzv[2*j2 + 1]);
  unsigned short* dst = g_v16t + (size_t)(bh*HD_ + d) * S_ + s0 + sc;
  *(uint4*)(dst)     = *(uint4*)&w[0];
  *(uint4*)(dst + 8) = *(uint4*)&w[4];
}

// ------------------------------------------------ pass 2: out[q,:] = sum_k exp(s_qk) * V'[k,:]
// 512-thread blocks: 8 waves x 32 q = 256 q share one K/V staging (LDS-per-wave halved).
// XCD-grouped 1D grid (1024): bid = (g&7) + 8*qi + 64*(g>>3), g = bh*4 + z, qi = q-block.
// P stays in REGISTERS via consistent key-slot permutation pi on both PV operands.
__global__ __launch_bounds__(512, 4) void k_pass2(){
  __shared__ __align__(16) unsigned short Ks[2][64*64];  // [buf][k][d] swizzled
  __shared__ __align__(16) unsigned short Vs[2][64*64];  // [buf][d][slot] swizzled, pi-permuted
  const int t = threadIdx.x, l = t & 63, wid = t >> 6;   // wid 0..7
  const int bid = blockIdx.x;
  const int g  = (bid & 7) | ((bid >> 6) << 3);   // 0..127
  const int bh = g >> 2;
  const int z  = g & 3;
  const int q0 = ((bid >> 3) & 7) * 256;
  const int b = bh >> 4, hh = bh & 15;
  const unsigned short* Qp = g_q16  + (size_t)bh * S_ * HD_;
  const unsigned short* Kp = g_k16  + (size_t)bh * S_ * HD_;
  const unsigned short* Vp = g_v16t + (size_t)bh * HD_ * S_;
  float* Op = (z == 0) ? g_vp : (z == 1) ? g_p1 : (z == 2) ? g_p2 : g_p3;
  const int ql = l & 15, kq = l >> 4;
  const int qb = q0 + wid*32;

  bf16x8 qf[2][2];
  #pragma unroll
  for (int h = 0; h < 2; ++h){
    const unsigned short* qr = Qp + (size_t)(qb + h*16 + ql) * HD_ + kq * 8;
    qf[h][0] = *(const bf16x8*)(qr);
    qf[h][1] = *(const bf16x8*)(qr + 32);
  }
  f32x4 co[4][2];
  #pragma unroll
  for (int nd = 0; nd < 4; ++nd)
    #pragma unroll
    for (int h = 0; h < 2; ++h)
      #pragma unroll
      for (int r = 0; r < 4; ++r) co[nd][h][r] = 0.f;

  const int srow = t >> 3, j = t & 7;     // 512 threads: one 64-row tile, one 16B chunk each
  const int scb = j * 16;
  const int vsl = j >> 2, jp = j & 3;     // V pi-staging: 32-key half, 8B group
  const int kg0 = z * (S_/4);
  float4 kreg;
  uint2 vA, vB;

#define LOADREGS(KT) \
  { const int kk0 = kg0 + (KT)*64; \
    kreg = *(const float4*)((const char*)(Kp + (size_t)(kk0 + srow) * HD_) + scb); \
    const unsigned short* vb = Vp + (size_t)srow * S_ + kk0 + vsl*32 + jp*4; \
    vA = *(const uint2*)(vb); \
    vB = *(const uint2*)(vb + 16); }
#define WRITEBUF(BUF) \
  { const int off = srow*128 + (scb ^ ((srow & 7) << 4)); \
    *(float4*)((char*)Ks[BUF] + off) = kreg; \
    uint4 wv; wv.x = vA.x; wv.y = vA.y; wv.z = vB.x; wv.w = vB.y; \
    *(uint4*)((char*)Vs[BUF] + off) = wv; }

  LOADREGS(0);
  WRITEBUF(0);
  LOADREGS(1);
  __syncthreads();

  for (int kt = 0; kt < 8; ++kt){
    const int k0 = kg0 + kt * 64;
    const int cur = kt & 1;
    if (kt < 7){ WRITEBUF(cur ^ 1); }
    if (kt < 6){ LOADREGS(kt + 2); }
    // ---- swapped QK^T: D[key16][q16]; A = K rows (LDS), B = Q (regs)
    f32x4 cst[4][2];
    #pragma unroll
    for (int kb = 0; kb < 4; ++kb)
      #pragma unroll
      for (int h = 0; h < 2; ++h)
        #pragma unroll
        for (int r = 0; r < 4; ++r) cst[kb][h][r] = 0.f;
    #pragma unroll
    for (int kb = 0; kb < 4; ++kb){
      const int row = kb*16 + ql;
      #pragma unroll
      for (int s = 0; s < 2; ++s){
        bf16x8 kf = *(const bf16x8*)((const char*)Ks[cur] + row*128 + ((s*64 + kq*16) ^ ((row & 7) << 4)));
        cst[kb][0] = MFMA16(kf, qf[0][s], cst[kb][0]);
        cst[kb][1] = MFMA16(kf, qf[1][s], cst[kb][1]);
      }
    }
    // ---- exp -> bf16 pair words, kept in registers (diag wave-uniform)
    const bool diag = (k0 < qb + 32) && (qb < k0 + 64);
    uint2 Pr[2][4];
    #pragma unroll
    for (int h = 0; h < 2; ++h){
      const int qg = qb + h*16 + ql;
      #pragma unroll
      for (int kb = 0; kb < 4; ++kb){
        float e[4];
        if (diag){
          #pragma unroll
          for (int r = 0; r < 4; ++r){
            const int key = k0 + kb*16 + kq*4 + r;
            e[r] = (qg == key) ? 1.0f : exp2f(cst[kb][h][r]);
          }
        } else {
          #pragma unroll
          for (int r = 0; r < 4; ++r) e[r] = exp2f(cst[kb][h][r]);
        }
        Pr[h][kb].x = cvtpk(e[0], e[1]);
        Pr[h][kb].y = cvtpk(e[2], e[3]);
      }
    }
    // ---- PV: D[q16][d16]; A = lane's own P words (pi order), B = Vs (pi-permuted)
    #pragma unroll
    for (int g2 = 0; g2 < 2; ++g2){          // 32-key group
      union { unsigned u[4]; bf16x8 v; } ap0, ap1;
      ap0.u[0] = Pr[0][2*g2].x;   ap0.u[1] = Pr[0][2*g2].y;
      ap0.u[2] = Pr[0][2*g2+1].x; ap0.u[3] = Pr[0][2*g2+1].y;
      ap1.u[0] = Pr[1][2*g2].x;   ap1.u[1] = Pr[1][2*g2].y;
      ap1.u[2] = Pr[1][2*g2+1].x; ap1.u[3] = Pr[1][2*g2+1].y;
      #pragma unroll
      for (int nd = 0; nd < 4; ++nd){
        const int row = nd*16 + ql;
        bf16x8 vf = *(const bf16x8*)((const char*)Vs[cur] + row*128 + ((g2*64 + kq*16) ^ ((row & 7) << 4)));
        co[nd][0] = MFMA16(ap0.v, vf, co[nd][0]);
        co[nd][1] = MFMA16(ap1.v, vf, co[nd][1]);
      }
    }
    __syncthreads();
  }
#undef LOADREGS
#undef WRITEBUF
  // epilogue: fp32 partial, (b,s,D) layout
  #pragma unroll
  for (int h = 0; h < 2; ++h){
    #pragma unroll
    for (int nd = 0; nd < 4; ++nd){
      const int d = nd*16 + ql;
      #pragma unroll
      for (int r = 0; r < 4; ++r){
        const int q = qb + h*16 + kq*4 + r;
        Op[(size_t)(b*S_ + q) * D_ + hh*HD_ + d] = co[nd][h][r];
      }
    }
  }
}

// ------------------------------------------------ combine 4 PV partials -> bf16
__global__ void k_reduce(){
  const int i = blockIdx.x * 256 + threadIdx.x;
  const size_t off = (size_t)i * 8;
  float4 a0 = *(const float4*)(g_vp + off), a1 = *(const float4*)(g_vp + off + 4);
  float4 b0 = *(const float4*)(g_p1 + off), b1 = *(const float4*)(g_p1 + off + 4);
  float4 c0 = *(const float4*)(g_p2 + off), c1 = *(const float4*)(g_p2 + off + 4);
  float4 d0 = *(const float4*)(g_p3 + off), d1 = *(const float4*)(g_p3 + off + 4);
  uint4 w;
  w.x = cvtpk(a0.x + b0.x + c0.x + d0.x, a0.y + b0.y + c0.y + d0.y);
  w.y = cvtpk(a0.z + b0.z + c0.z + d0.z, a0.w + b0.w + c0.w + d0.w);
  w.z = cvtpk(a1.x + b1.x + c1.x + d1.x, a1.y + b1.y + c1.y + d1.y);
  w.w = cvtpk(a1.z + b1.z + c1.z + d1.z, a1.w + b1.w + c1.w + d1.w);
  *(uint4*)(g_x16 + off) = w;
}

extern "C" void kernel_launch(void* const* d_in, const int* in_sizes, int n_in,
                              void* d_out, int out_size, void* d_ws, size_t ws_size,
                              hipStream_t stream) {
  const float* query = (const float*)d_in[0];
  const float* key   = (const float*)d_in[1];
  const float* value = (const float*)d_in[2];
  const int*   pos   = (const int*)  d_in[3];
  const float* Wk    = (const float*)d_in[4];
  const float* bk    = (const float*)d_in[5];
  const float* Wv    = (const float*)d_in[6];
  const float* bv    = (const float*)d_in[7];
  const float* Wo    = (const float*)d_in[8];
  const float* bo    = (const float*)d_in[9];
  float* out = (float*)d_out;

  k_table<<<256, 256, 0, stream>>>(pos);
  k_cvt5<<<dim3(2048, 1, 5), 256, 0, stream>>>(key, value, Wk, Wv, Wo);

  dim3 gP(D_/128, M_/128, 2);   // (8, 32, 2)
  k_proj<<<gP, 256, 0, stream>>>(bk, bv);                      // -> g_k16 (roped bf16), g_vp (roped fp32)

  k_ropeq<<<8192, 256, 0, stream>>>(query);                    // -> g_q16 (roped, scaled)

  k_pass1<<<1024, 256, 0, stream>>>();                         // -> g_rz  (XCD-grouped)
  k_vfix <<<dim3(32, BH_), 256, 0, stream>>>();                // g_vp -> g_v16t (*1/Z, transposed)
  k_pass2<<<1024, 512, 0, stream>>>();                         // -> 4 fp32 partials (XCD-grouped, 8-wave blocks)
  k_reduce<<<(M_*D_/8)/256, 256, 0, stream>>>();               // -> g_x16

  dim3 gO(D_/128, M_/128);      // (8, 32)
  k_gemm_out<<<gO, 256, 0, stream>>>(bo, out);                 // output proj
}